// Round 1
// baseline (231.549 us; speedup 1.0000x reference)
//
#include <hip/hip_runtime.h>
#include <stdint.h>

typedef __bf16 bf16;
typedef __bf16 bf16x8 __attribute__((ext_vector_type(8)));
typedef float f32x4 __attribute__((ext_vector_type(4)));

#define T_TOT 6144
#define E_DIM 1024
#define NHEAD 16

// cu offsets for LENGTHS = [1024,512,768,896,1024,640,384,896] (compile-time in reference)
// all lengths are multiples of 64.

// ---------------- convert f32 -> bf16 (vectorized) ----------------
__global__ __launch_bounds__(256) void cvt_bf16_kernel(const float* __restrict__ src,
                                                       bf16* __restrict__ dst, int n) {
    int i = (blockIdx.x * 256 + threadIdx.x) * 4;
    if (i >= n) return;
    float4 v = *reinterpret_cast<const float4*>(src + i);
    union { bf16 h[4]; uint2 u; } pk;
    pk.h[0] = (bf16)v.x; pk.h[1] = (bf16)v.y; pk.h[2] = (bf16)v.z; pk.h[3] = (bf16)v.w;
    *reinterpret_cast<uint2*>(dst + i) = pk.u;
}

// ---------------- GEMM: C[M][N] = A[M][K] @ BT[N][K]^T (+bias) ----------------
// BM=BN=128, BK=32, 4 waves, each wave 64x64 (4x4 mfma_f32_16x16x32_bf16 fragments).
// LDS tiles padded to stride 40 bf16 (80B) -> 2-way bank aliasing only (free).
__device__ __forceinline__ void gemm_body(const bf16* __restrict__ A,
                                          const bf16* __restrict__ BT,
                                          const float* __restrict__ bias,
                                          void* __restrict__ Cout,
                                          bool out_f32, int M, int N, int K) {
    __shared__ bf16 As[128][40];
    __shared__ bf16 Bs[128][40];
    const int tid  = threadIdx.x;
    const int lane = tid & 63;
    const int wid  = tid >> 6;
    const int l15  = lane & 15, l4 = lane >> 4;
    const int wr   = wid >> 1, wc = wid & 1;
    const int bm   = blockIdx.x, bn = blockIdx.y;

    f32x4 acc[4][4] = {};

    // staging map: 512 chunks of 8 bf16; chunk c -> row=c>>2, k8=(c&3)*8
    const int r0 = tid >> 2;              // rows 0..63
    const int k8 = (tid & 3) * 8;
    const int r1 = r0 + 64;               // rows 64..127

    const bf16* Ag = A  + (size_t)bm * 128 * K;
    const bf16* Bg = BT + (size_t)bn * 128 * K;

    for (int k0 = 0; k0 < K; k0 += 32) {
        uint4 va0 = *reinterpret_cast<const uint4*>(Ag + (size_t)r0 * K + k0 + k8);
        uint4 va1 = *reinterpret_cast<const uint4*>(Ag + (size_t)r1 * K + k0 + k8);
        uint4 vb0 = *reinterpret_cast<const uint4*>(Bg + (size_t)r0 * K + k0 + k8);
        uint4 vb1 = *reinterpret_cast<const uint4*>(Bg + (size_t)r1 * K + k0 + k8);
        *reinterpret_cast<uint4*>(&As[r0][k8]) = va0;
        *reinterpret_cast<uint4*>(&As[r1][k8]) = va1;
        *reinterpret_cast<uint4*>(&Bs[r0][k8]) = vb0;
        *reinterpret_cast<uint4*>(&Bs[r1][k8]) = vb1;
        __syncthreads();

        bf16x8 af[4], bfr[4];
        #pragma unroll
        for (int m = 0; m < 4; ++m)
            af[m] = *reinterpret_cast<const bf16x8*>(&As[wr * 64 + m * 16 + l15][l4 * 8]);
        #pragma unroll
        for (int n = 0; n < 4; ++n)
            bfr[n] = *reinterpret_cast<const bf16x8*>(&Bs[wc * 64 + n * 16 + l15][l4 * 8]);
        #pragma unroll
        for (int m = 0; m < 4; ++m)
            #pragma unroll
            for (int n = 0; n < 4; ++n)
                acc[m][n] = __builtin_amdgcn_mfma_f32_16x16x32_bf16(af[m], bfr[n], acc[m][n], 0, 0, 0);
        __syncthreads();
    }

    // epilogue: D layout row=(lane>>4)*4+r, col=lane&15 (m89/m91-verified)
    #pragma unroll
    for (int n = 0; n < 4; ++n) {
        const int col  = bn * 128 + wc * 64 + n * 16 + l15;
        const float bc = bias ? bias[col] : 0.0f;
        #pragma unroll
        for (int m = 0; m < 4; ++m) {
            const int rowb = bm * 128 + wr * 64 + m * 16 + l4 * 4;
            #pragma unroll
            for (int r = 0; r < 4; ++r) {
                float val = acc[m][n][r] + bc;
                if (out_f32)
                    reinterpret_cast<float*>(Cout)[(size_t)(rowb + r) * N + col] = val;
                else
                    reinterpret_cast<bf16*>(Cout)[(size_t)(rowb + r) * N + col] = (bf16)val;
            }
        }
    }
}

__global__ __launch_bounds__(256, 2) void qkv_gemm_kernel(
        const bf16* __restrict__ hsb,
        const bf16* __restrict__ wq, const bf16* __restrict__ wk, const bf16* __restrict__ wv,
        const float* __restrict__ bq, const float* __restrict__ bv,
        bf16* __restrict__ q, bf16* __restrict__ k, bf16* __restrict__ v) {
    const int z = blockIdx.z;
    const bf16* W    = (z == 0) ? wq : ((z == 1) ? wk : wv);
    const float* bias = (z == 0) ? bq : ((z == 1) ? nullptr : bv);
    bf16* out        = (z == 0) ? q : ((z == 1) ? k : v);
    gemm_body(hsb, W, bias, out, false, T_TOT, E_DIM, E_DIM);
}

__global__ __launch_bounds__(256, 2) void out_gemm_kernel(
        const bf16* __restrict__ attnb, const bf16* __restrict__ wo,
        const float* __restrict__ bo, float* __restrict__ out) {
    gemm_body(attnb, wo, bo, out, true, T_TOT, E_DIM, E_DIM);
}

// ---------------- RoPE in-place on q,k ----------------
// thread owns pair (d, d+32) of one (t,h): safe in-place.
__global__ __launch_bounds__(256) void rope_kernel(bf16* __restrict__ q, bf16* __restrict__ k,
                                                   const float* __restrict__ cosb,
                                                   const float* __restrict__ sinb) {
    int idx = blockIdx.x * 256 + threadIdx.x;           // T*16*32
    if (idx >= T_TOT * NHEAD * 32) return;
    int dp = idx & 31;
    int h  = (idx >> 5) & 15;
    int t  = idx >> 9;
    float c0 = cosb[t * 64 + dp],      s0 = sinb[t * 64 + dp];
    float c1 = cosb[t * 64 + dp + 32], s1 = sinb[t * 64 + dp + 32];
    size_t o0 = (size_t)t * E_DIM + h * 64 + dp;
    size_t o1 = o0 + 32;
    float q0 = (float)q[o0], q1 = (float)q[o1];
    q[o0] = (bf16)(q0 * c0 - q1 * s0);
    q[o1] = (bf16)(q1 * c1 + q0 * s1);
    float k0 = (float)k[o0], k1 = (float)k[o1];
    k[o0] = (bf16)(k0 * c0 - k1 * s0);
    k[o1] = (bf16)(k1 * c1 + k0 * s1);
}

// ---------------- V transpose: vt[h*64+d][t] = v[t][h*64+d] ----------------
__global__ __launch_bounds__(256) void transpose_v_kernel(const bf16* __restrict__ v,
                                                          bf16* __restrict__ vt) {
    __shared__ bf16 tile[64][72];
    const int h  = blockIdx.x & 15;
    const int t0 = (blockIdx.x >> 4) * 64;
    const int tid = threadIdx.x;
    #pragma unroll
    for (int i = 0; i < 2; ++i) {
        int c = tid + i * 256;            // 0..511
        int r = c >> 3, c8 = (c & 7) * 8;
        *reinterpret_cast<uint4*>(&tile[r][c8]) =
            *reinterpret_cast<const uint4*>(v + (size_t)(t0 + r) * E_DIM + h * 64 + c8);
    }
    __syncthreads();
    #pragma unroll
    for (int i = 0; i < 2; ++i) {
        int c = tid + i * 256;
        int d = c >> 3, t8 = (c & 7) * 8;
        bf16 tmp[8];
        #pragma unroll
        for (int j = 0; j < 8; ++j) tmp[j] = tile[t8 + j][d];
        *reinterpret_cast<uint4*>(vt + (size_t)(h * 64 + d) * T_TOT + t0 + t8) =
            *reinterpret_cast<uint4*>(tmp);
    }
}

// ---------------- flash attention (varlen causal) ----------------
// block = (64-row q tile, head); 4 independent waves of 16 q rows.
__global__ __launch_bounds__(256, 2) void attn_kernel(const bf16* __restrict__ q,
                                                      const bf16* __restrict__ k,
                                                      const bf16* __restrict__ vt,
                                                      bf16* __restrict__ attn) {
    const int cu[9] = {0, 1024, 1536, 2304, 3200, 4224, 4864, 5248, 6144};
    __shared__ bf16 p_lds[4][16][72];   // per-wave P staging, padded
    const int h   = blockIdx.x & 15;
    const int qt  = blockIdx.x >> 4;
    const int tid = threadIdx.x, lane = tid & 63, wid = tid >> 6;
    const int l15 = lane & 15, l4 = lane >> 4;

    const int tq0 = qt * 64;
    int b = 0;
    #pragma unroll
    for (int i = 0; i < 8; ++i) if (tq0 >= cu[i + 1]) b = i + 1;
    const int q0 = tq0 + wid * 16;        // global token of wave's first row
    const int p0 = q0 - cu[b];            // local position in sequence

    // Q fragments (A-operand): row=lane&15, k=(lane>>4)*8+b
    bf16x8 qf[2];
    #pragma unroll
    for (int kk = 0; kk < 2; ++kk)
        qf[kk] = *reinterpret_cast<const bf16x8*>(
            q + (size_t)(q0 + l15) * E_DIM + h * 64 + kk * 32 + l4 * 8);

    f32x4 o[4] = {};
    float mrow[4], lrow[4];
    #pragma unroll
    for (int r = 0; r < 4; ++r) { mrow[r] = -1e30f; lrow[r] = 0.0f; }

    const int nkt = ((p0 + 15) >> 6) + 1;
    const size_t kbase = (size_t)cu[b] * E_DIM + h * 64;

    for (int kt = 0; kt < nkt; ++kt) {
        const int j0 = kt * 64;
        // S = Q K^T
        f32x4 s[4] = {};
        #pragma unroll
        for (int nt = 0; nt < 4; ++nt) {
            #pragma unroll
            for (int kk = 0; kk < 2; ++kk) {
                bf16x8 kf = *reinterpret_cast<const bf16x8*>(
                    k + kbase + (size_t)(j0 + nt * 16 + l15) * E_DIM + kk * 32 + l4 * 8);
                s[nt] = __builtin_amdgcn_mfma_f32_16x16x32_bf16(qf[kk], kf, s[nt], 0, 0, 0);
            }
        }
        // scale + causal mask + online softmax (per row r, rows = l4*4+r)
        #pragma unroll
        for (int r = 0; r < 4; ++r) {
            const int rowp = p0 + l4 * 4 + r;
            float tmax = -1e30f;
            #pragma unroll
            for (int nt = 0; nt < 4; ++nt) {
                const int colp = j0 + nt * 16 + l15;
                float sv = s[nt][r] * 0.125f;
                sv = (colp <= rowp) ? sv : -1e30f;
                s[nt][r] = sv;
                tmax = fmaxf(tmax, sv);
            }
            #pragma unroll
            for (int off = 1; off < 16; off <<= 1)
                tmax = fmaxf(tmax, __shfl_xor(tmax, off));
            const float mnew = fmaxf(mrow[r], tmax);
            const float alpha = __expf(mrow[r] - mnew);
            float rs = 0.0f;
            #pragma unroll
            for (int nt = 0; nt < 4; ++nt) {
                float p = __expf(s[nt][r] - mnew);
                p_lds[wid][l4 * 4 + r][nt * 16 + l15] = (bf16)p;
                rs += p;
            }
            #pragma unroll
            for (int off = 1; off < 16; off <<= 1)
                rs += __shfl_xor(rs, off);
            lrow[r] = lrow[r] * alpha + rs;
            mrow[r] = mnew;
            #pragma unroll
            for (int nt = 0; nt < 4; ++nt) o[nt][r] *= alpha;
        }
        // P fragments (A-operand of PV) from LDS
        bf16x8 pf[2];
        #pragma unroll
        for (int kk = 0; kk < 2; ++kk)
            pf[kk] = *reinterpret_cast<const bf16x8*>(&p_lds[wid][l15][kk * 32 + l4 * 8]);
        // O += P V  (B-operand from vt, contiguous along t)
        #pragma unroll
        for (int nt = 0; nt < 4; ++nt) {
            #pragma unroll
            for (int kk = 0; kk < 2; ++kk) {
                bf16x8 vf = *reinterpret_cast<const bf16x8*>(
                    vt + (size_t)(h * 64 + nt * 16 + l15) * T_TOT + cu[b] + j0 + kk * 32 + l4 * 8);
                o[nt] = __builtin_amdgcn_mfma_f32_16x16x32_bf16(pf[kk], vf, o[nt], 0, 0, 0);
            }
        }
    }
    // epilogue: normalize and store bf16
    #pragma unroll
    for (int nt = 0; nt < 4; ++nt) {
        #pragma unroll
        for (int r = 0; r < 4; ++r) {
            float val = o[nt][r] / lrow[r];
            attn[(size_t)(q0 + l4 * 4 + r) * E_DIM + h * 64 + nt * 16 + l15] = (bf16)val;
        }
    }
}

extern "C" void kernel_launch(void* const* d_in, const int* in_sizes, int n_in,
                              void* d_out, int out_size, void* d_ws, size_t ws_size,
                              hipStream_t stream) {
    const float* hs   = (const float*)d_in[0];
    // d_in[1] = seq_len (compile-time constants, unused)
    const float* cosb = (const float*)d_in[2];
    const float* sinb = (const float*)d_in[3];
    const float* Wq   = (const float*)d_in[4];
    const float* bq   = (const float*)d_in[5];
    const float* Wk   = (const float*)d_in[6];
    const float* Wv   = (const float*)d_in[7];
    const float* bv   = (const float*)d_in[8];
    const float* Wo   = (const float*)d_in[9];
    const float* bo   = (const float*)d_in[10];

    const size_t TE = (size_t)T_TOT * E_DIM;   // 6291456
    const size_t EE = (size_t)E_DIM * E_DIM;   // 1048576

    char* w = (char*)d_ws;
    bf16* hsb  = (bf16*)w; w += TE * 2;
    bf16* wqb  = (bf16*)w; w += EE * 2;
    bf16* wkb  = (bf16*)w; w += EE * 2;
    bf16* wvb  = (bf16*)w; w += EE * 2;
    bf16* wob  = (bf16*)w; w += EE * 2;
    bf16* qb   = (bf16*)w; w += TE * 2;
    bf16* kb   = (bf16*)w; w += TE * 2;
    bf16* vb   = (bf16*)w; w += TE * 2;
    bf16* vtb  = (bf16*)w; w += TE * 2;
    bf16* attnb= (bf16*)w; w += TE * 2;

    // 1) converts
    cvt_bf16_kernel<<<(int)(TE / 4 / 256), 256, 0, stream>>>(hs, hsb, (int)TE);
    cvt_bf16_kernel<<<(int)(EE / 4 / 256), 256, 0, stream>>>(Wq, wqb, (int)EE);
    cvt_bf16_kernel<<<(int)(EE / 4 / 256), 256, 0, stream>>>(Wk, wkb, (int)EE);
    cvt_bf16_kernel<<<(int)(EE / 4 / 256), 256, 0, stream>>>(Wv, wvb, (int)EE);
    cvt_bf16_kernel<<<(int)(EE / 4 / 256), 256, 0, stream>>>(Wo, wob, (int)EE);

    // 2) fused QKV GEMM
    dim3 gqkv(T_TOT / 128, E_DIM / 128, 3);
    qkv_gemm_kernel<<<gqkv, 256, 0, stream>>>(hsb, wqb, wkb, wvb, bq, bv, qb, kb, vb);

    // 3) RoPE in-place on q,k
    rope_kernel<<<(T_TOT * NHEAD * 32) / 256, 256, 0, stream>>>(qb, kb, cosb, sinb);

    // 4) V transpose
    transpose_v_kernel<<<(T_TOT / 64) * NHEAD, 256, 0, stream>>>(vb, vtb);

    // 5) attention
    attn_kernel<<<(T_TOT / 64) * NHEAD, 256, 0, stream>>>(qb, kb, vtb, attnb);

    // 6) output projection -> f32 d_out
    dim3 gout(T_TOT / 128, E_DIM / 128, 1);
    out_gemm_kernel<<<gout, 256, 0, stream>>>(attnb, wob, bo, (float*)d_out);
}

// Round 2
// 168.140 us; speedup vs baseline: 1.3771x; 1.3771x over previous
//
#include <hip/hip_runtime.h>
#include <stdint.h>

typedef __bf16 bf16;
typedef __bf16 bf16x8 __attribute__((ext_vector_type(8)));
typedef float f32x4 __attribute__((ext_vector_type(4)));

#define T_TOT 6144
#define E_DIM 1024
#define NHEAD 16

// async global->LDS, 16B per lane; LDS dest = wave-uniform base + lane*16
__device__ __forceinline__ void gload16(const void* g, void* l) {
    __builtin_amdgcn_global_load_lds((const __attribute__((address_space(1))) void*)g,
                                     (__attribute__((address_space(3))) void*)l, 16, 0, 0);
}

// ---------------- converts ----------------
__global__ __launch_bounds__(256) void cvt_bf16_kernel(const float* __restrict__ src,
                                                       bf16* __restrict__ dst, int n) {
    int i = (blockIdx.x * 256 + threadIdx.x) * 4;
    if (i >= n) return;
    float4 v = *reinterpret_cast<const float4*>(src + i);
    union { bf16 h[4]; uint2 u; } pk;
    pk.h[0] = (bf16)v.x; pk.h[1] = (bf16)v.y; pk.h[2] = (bf16)v.z; pk.h[3] = (bf16)v.w;
    *reinterpret_cast<uint2*>(dst + i) = pk.u;
}

__global__ __launch_bounds__(256) void cvt4_bf16_kernel(const float* __restrict__ w0,
                                                        const float* __restrict__ w1,
                                                        const float* __restrict__ w2,
                                                        const float* __restrict__ w3,
                                                        bf16* __restrict__ d0, bf16* __restrict__ d1,
                                                        bf16* __restrict__ d2, bf16* __restrict__ d3) {
    const float* src = (blockIdx.y == 0) ? w0 : (blockIdx.y == 1) ? w1 : (blockIdx.y == 2) ? w2 : w3;
    bf16* dst        = (blockIdx.y == 0) ? d0 : (blockIdx.y == 1) ? d1 : (blockIdx.y == 2) ? d2 : d3;
    int i = (blockIdx.x * 256 + threadIdx.x) * 4;
    float4 v = *reinterpret_cast<const float4*>(src + i);
    union { bf16 h[4]; uint2 u; } pk;
    pk.h[0] = (bf16)v.x; pk.h[1] = (bf16)v.y; pk.h[2] = (bf16)v.z; pk.h[3] = (bf16)v.w;
    *reinterpret_cast<uint2*>(dst + i) = pk.u;
}

// ---------------- GEMM (m97 structure): C = A @ BT^T (+bias) ----------------
// BM=BN=128, BK=32, 4 waves x (64x64), global_load_lds width-16 staging, linear LDS.
__device__ __forceinline__ void gemm_body(const bf16* __restrict__ A,
                                          const bf16* __restrict__ BT,
                                          const float* __restrict__ bias,
                                          void* __restrict__ Cout,
                                          bool out_f32, int N, int K) {
    __shared__ bf16 As[128 * 32];
    __shared__ bf16 Bs[128 * 32];
    const int tid  = threadIdx.x;
    const int lane = tid & 63;
    const int wid  = tid >> 6;
    const int l15  = lane & 15, l4 = lane >> 4;
    const int wr   = wid >> 1, wc = wid & 1;
    const int bm   = blockIdx.x, bn = blockIdx.y;

    f32x4 acc[4][4] = {};

    const bf16* Ag = A  + (size_t)bm * 128 * K;
    const bf16* Bg = BT + (size_t)bn * 128 * K;

    for (int k0 = 0; k0 < K; k0 += 32) {
        #pragma unroll
        for (int j = 0; j < 2; ++j) {
            const int c   = j * 256 + wid * 64 + lane;   // chunk 0..511
            const int row = c >> 2, c4 = c & 3;
            gload16(Ag + (size_t)row * K + k0 + c4 * 8, As + (size_t)(j * 256 + wid * 64) * 8);
            gload16(Bg + (size_t)row * K + k0 + c4 * 8, Bs + (size_t)(j * 256 + wid * 64) * 8);
        }
        __syncthreads();

        bf16x8 af[4], bfr[4];
        #pragma unroll
        for (int m = 0; m < 4; ++m)
            af[m] = *reinterpret_cast<const bf16x8*>(&As[(wr * 64 + m * 16 + l15) * 32 + l4 * 8]);
        #pragma unroll
        for (int n = 0; n < 4; ++n)
            bfr[n] = *reinterpret_cast<const bf16x8*>(&Bs[(wc * 64 + n * 16 + l15) * 32 + l4 * 8]);
        #pragma unroll
        for (int m = 0; m < 4; ++m)
            #pragma unroll
            for (int n = 0; n < 4; ++n)
                acc[m][n] = __builtin_amdgcn_mfma_f32_16x16x32_bf16(af[m], bfr[n], acc[m][n], 0, 0, 0);
        __syncthreads();
    }

    #pragma unroll
    for (int n = 0; n < 4; ++n) {
        const int col  = bn * 128 + wc * 64 + n * 16 + l15;
        const float bc = bias ? bias[col] : 0.0f;
        #pragma unroll
        for (int m = 0; m < 4; ++m) {
            const int rowb = bm * 128 + wr * 64 + m * 16 + l4 * 4;
            #pragma unroll
            for (int r = 0; r < 4; ++r) {
                float val = acc[m][n][r] + bc;
                if (out_f32)
                    reinterpret_cast<float*>(Cout)[(size_t)(rowb + r) * N + col] = val;
                else
                    reinterpret_cast<bf16*>(Cout)[(size_t)(rowb + r) * N + col] = (bf16)val;
            }
        }
    }
}

__global__ __launch_bounds__(256, 3) void qkv_gemm_kernel(
        const bf16* __restrict__ hsb,
        const bf16* __restrict__ wq, const bf16* __restrict__ wk, const bf16* __restrict__ wv,
        const float* __restrict__ bq, const float* __restrict__ bv,
        bf16* __restrict__ q, bf16* __restrict__ k, bf16* __restrict__ v) {
    const int z = blockIdx.z;
    const bf16* W     = (z == 0) ? wq : ((z == 1) ? wk : wv);
    const float* bias = (z == 0) ? bq : ((z == 1) ? nullptr : bv);
    bf16* out         = (z == 0) ? q : ((z == 1) ? k : v);
    gemm_body(hsb, W, bias, out, false, E_DIM, E_DIM);
}

__global__ __launch_bounds__(256, 3) void out_gemm_kernel(
        const bf16* __restrict__ attnb, const bf16* __restrict__ wo,
        const float* __restrict__ bo, float* __restrict__ out) {
    gemm_body(attnb, wo, bo, out, true, E_DIM, E_DIM);
}

// ---------------- RoPE in-place on q,k (vectorized 8-wide) ----------------
__global__ __launch_bounds__(256) void rope_kernel(bf16* __restrict__ q, bf16* __restrict__ k,
                                                   const float* __restrict__ cosb,
                                                   const float* __restrict__ sinb) {
    int idx = blockIdx.x * 256 + threadIdx.x;           // T*16*4
    int j = idx & 3;
    int h = (idx >> 2) & 15;
    int t = idx >> 6;
    const int d0 = j * 8;
    float cl[8], ch[8], sl[8], sh[8];
    #pragma unroll
    for (int e = 0; e < 8; ++e) {
        cl[e] = cosb[t * 64 + d0 + e];
        ch[e] = cosb[t * 64 + d0 + 32 + e];
        sl[e] = sinb[t * 64 + d0 + e];
        sh[e] = sinb[t * 64 + d0 + 32 + e];
    }
    size_t o0 = (size_t)t * E_DIM + h * 64 + d0;
    size_t o1 = o0 + 32;
    bf16x8 qlo = *reinterpret_cast<bf16x8*>(q + o0);
    bf16x8 qhi = *reinterpret_cast<bf16x8*>(q + o1);
    bf16x8 klo = *reinterpret_cast<bf16x8*>(k + o0);
    bf16x8 khi = *reinterpret_cast<bf16x8*>(k + o1);
    bf16x8 qlo2, qhi2, klo2, khi2;
    #pragma unroll
    for (int e = 0; e < 8; ++e) {
        float ql = (float)qlo[e], qh = (float)qhi[e];
        qlo2[e] = (bf16)(ql * cl[e] - qh * sl[e]);
        qhi2[e] = (bf16)(qh * ch[e] + ql * sh[e]);
        float kl = (float)klo[e], kh = (float)khi[e];
        klo2[e] = (bf16)(kl * cl[e] - kh * sl[e]);
        khi2[e] = (bf16)(kh * ch[e] + kl * sh[e]);
    }
    *reinterpret_cast<bf16x8*>(q + o0) = qlo2;
    *reinterpret_cast<bf16x8*>(q + o1) = qhi2;
    *reinterpret_cast<bf16x8*>(k + o0) = klo2;
    *reinterpret_cast<bf16x8*>(k + o1) = khi2;
}

// ---------------- V transpose: vt[h*64+d][t] = v[t][h*64+d] ----------------
__global__ __launch_bounds__(256) void transpose_v_kernel(const bf16* __restrict__ v,
                                                          bf16* __restrict__ vt) {
    __shared__ bf16 tile[64][72];
    const int h  = blockIdx.x & 15;
    const int t0 = (blockIdx.x >> 4) * 64;
    const int tid = threadIdx.x;
    #pragma unroll
    for (int i = 0; i < 2; ++i) {
        int c = tid + i * 256;
        int r = c >> 3, c8 = (c & 7) * 8;
        *reinterpret_cast<uint4*>(&tile[r][c8]) =
            *reinterpret_cast<const uint4*>(v + (size_t)(t0 + r) * E_DIM + h * 64 + c8);
    }
    __syncthreads();
    #pragma unroll
    for (int i = 0; i < 2; ++i) {
        int c = tid + i * 256;
        int d = c >> 3, t8 = (c & 7) * 8;
        bf16 tmp[8];
        #pragma unroll
        for (int jj = 0; jj < 8; ++jj) tmp[jj] = tile[t8 + jj][d];
        *reinterpret_cast<uint4*>(vt + (size_t)(h * 64 + d) * T_TOT + t0 + t8) =
            *reinterpret_cast<uint4*>(tmp);
    }
}

// ---------------- flash attention (varlen causal), LDS-staged K/V ----------------
// Tiles are [64][64] bf16 in linear LDS; logical (row, col8) lives at chunk
// row*8 + (col8 ^ (row&7))  (inverse-swizzled global source, m173 pattern).
__device__ __forceinline__ void stage_kv(const bf16* __restrict__ kp, const bf16* __restrict__ vtp,
                                         bf16* kls, bf16* vls, int tok0, int h,
                                         int wid, int lane) {
    #pragma unroll
    for (int j = 0; j < 2; ++j) {
        const int c   = j * 256 + wid * 64 + lane;   // chunk 0..511
        const int row = c >> 3;
        const int c8s = (c & 7) ^ (row & 7);
        gload16(kp  + (size_t)(tok0 + row) * E_DIM + h * 64 + c8s * 8,
                kls + (size_t)(j * 256 + wid * 64) * 8);
        gload16(vtp + (size_t)(h * 64 + row) * T_TOT + tok0 + c8s * 8,
                vls + (size_t)(j * 256 + wid * 64) * 8);
    }
}

// element index of the 8-elem group (row j, col8) under the XOR swizzle
__device__ __forceinline__ int swz(int j, int col8) {
    return j * 64 + ((col8 ^ (j & 7)) << 3);
}

__global__ __launch_bounds__(256, 3) void attn_kernel(const bf16* __restrict__ q,
                                                      const bf16* __restrict__ k,
                                                      const bf16* __restrict__ vt,
                                                      bf16* __restrict__ attn) {
    const int cu[9] = {0, 1024, 1536, 2304, 3200, 4224, 4864, 5248, 6144};
    __shared__ bf16 kls[2][64 * 64];
    __shared__ bf16 vls[2][64 * 64];
    __shared__ bf16 p_lds[4][16][72];
    const int h   = blockIdx.x & 15;
    const int qt  = blockIdx.x >> 4;
    const int tid = threadIdx.x, lane = tid & 63, wid = tid >> 6;
    const int l15 = lane & 15, l4 = lane >> 4;

    const int tq0 = qt * 64;
    int b = 0;
    #pragma unroll
    for (int i = 0; i < 8; ++i) if (tq0 >= cu[i + 1]) b = i + 1;
    const int q0  = tq0 + wid * 16;       // wave's first global token
    const int p0  = q0 - cu[b];           // wave's first local position
    const int p0b = tq0 - cu[b];          // block's first local position
    const int nkt = (p0b >> 6) + 1;       // K tiles for the whole block

    bf16x8 qf[2];
    #pragma unroll
    for (int kk = 0; kk < 2; ++kk)
        qf[kk] = *reinterpret_cast<const bf16x8*>(
            q + (size_t)(q0 + l15) * E_DIM + h * 64 + kk * 32 + l4 * 8);

    f32x4 o[4] = {};
    float mrow[4], lrow[4];
    #pragma unroll
    for (int r = 0; r < 4; ++r) { mrow[r] = -1e30f; lrow[r] = 0.0f; }

    stage_kv(k, vt, kls[0], vls[0], cu[b], h, wid, lane);
    __syncthreads();

    for (int kt = 0; kt < nkt; ++kt) {
        const int cur = kt & 1;
        if (kt + 1 < nkt)
            stage_kv(k, vt, kls[cur ^ 1], vls[cur ^ 1], cu[b] + (kt + 1) * 64, h, wid, lane);

        const int j0 = kt * 64;
        const bool diag = (kt == nkt - 1);

        // S = Q K^T
        f32x4 s[4] = {};
        #pragma unroll
        for (int nt = 0; nt < 4; ++nt) {
            #pragma unroll
            for (int kk = 0; kk < 2; ++kk) {
                bf16x8 kf = *reinterpret_cast<const bf16x8*>(&kls[cur][swz(nt * 16 + l15, kk * 4 + l4)]);
                s[nt] = __builtin_amdgcn_mfma_f32_16x16x32_bf16(qf[kk], kf, s[nt], 0, 0, 0);
            }
        }

        // scale + (diag) mask + online softmax; rows = l4*4+r
        #pragma unroll
        for (int r = 0; r < 4; ++r) {
            const int rowp = p0 + l4 * 4 + r;
            float tmax = -1e30f;
            #pragma unroll
            for (int nt = 0; nt < 4; ++nt) {
                float sv = s[nt][r] * 0.125f;
                if (diag) {
                    const int colp = j0 + nt * 16 + l15;
                    sv = (colp <= rowp) ? sv : -1e30f;
                }
                s[nt][r] = sv;
                tmax = fmaxf(tmax, sv);
            }
            #pragma unroll
            for (int off = 1; off < 16; off <<= 1)
                tmax = fmaxf(tmax, __shfl_xor(tmax, off));
            const float mnew  = fmaxf(mrow[r], tmax);
            const float alpha = __expf(mrow[r] - mnew);
            float rs = 0.0f;
            #pragma unroll
            for (int nt = 0; nt < 4; ++nt) {
                float p = __expf(s[nt][r] - mnew);
                p_lds[wid][l4 * 4 + r][nt * 16 + l15] = (bf16)p;
                rs += p;
            }
            #pragma unroll
            for (int off = 1; off < 16; off <<= 1)
                rs += __shfl_xor(rs, off);
            lrow[r] = lrow[r] * alpha + rs;
            mrow[r] = mnew;
            #pragma unroll
            for (int nt = 0; nt < 4; ++nt) o[nt][r] *= alpha;
        }

        // P fragments (A-operand of PV)
        bf16x8 pf[2];
        #pragma unroll
        for (int kk = 0; kk < 2; ++kk)
            pf[kk] = *reinterpret_cast<const bf16x8*>(&p_lds[wid][l15][kk * 32 + l4 * 8]);

        // O += P V
        #pragma unroll
        for (int nt = 0; nt < 4; ++nt) {
            #pragma unroll
            for (int kk = 0; kk < 2; ++kk) {
                bf16x8 vf = *reinterpret_cast<const bf16x8*>(&vls[cur][swz(nt * 16 + l15, kk * 4 + l4)]);
                o[nt] = __builtin_amdgcn_mfma_f32_16x16x32_bf16(pf[kk], vf, o[nt], 0, 0, 0);
            }
        }
        __syncthreads();
    }

    #pragma unroll
    for (int nt = 0; nt < 4; ++nt) {
        #pragma unroll
        for (int r = 0; r < 4; ++r) {
            float val = o[nt][r] / lrow[r];
            attn[(size_t)(q0 + l4 * 4 + r) * E_DIM + h * 64 + nt * 16 + l15] = (bf16)val;
        }
    }
}

extern "C" void kernel_launch(void* const* d_in, const int* in_sizes, int n_in,
                              void* d_out, int out_size, void* d_ws, size_t ws_size,
                              hipStream_t stream) {
    const float* hs   = (const float*)d_in[0];
    const float* cosb = (const float*)d_in[2];
    const float* sinb = (const float*)d_in[3];
    const float* Wq   = (const float*)d_in[4];
    const float* bq   = (const float*)d_in[5];
    const float* Wk   = (const float*)d_in[6];
    const float* Wv   = (const float*)d_in[7];
    const float* bv   = (const float*)d_in[8];
    const float* Wo   = (const float*)d_in[9];
    const float* bo   = (const float*)d_in[10];

    const size_t TE = (size_t)T_TOT * E_DIM;
    const size_t EE = (size_t)E_DIM * E_DIM;

    char* w = (char*)d_ws;
    bf16* hsb   = (bf16*)w; w += TE * 2;
    bf16* wqb   = (bf16*)w; w += EE * 2;
    bf16* wkb   = (bf16*)w; w += EE * 2;
    bf16* wvb   = (bf16*)w; w += EE * 2;
    bf16* wob   = (bf16*)w; w += EE * 2;
    bf16* qb    = (bf16*)w; w += TE * 2;
    bf16* kb    = (bf16*)w; w += TE * 2;
    bf16* vb    = (bf16*)w; w += TE * 2;
    bf16* vtb   = (bf16*)w; w += TE * 2;
    bf16* attnb = (bf16*)w; w += TE * 2;

    cvt_bf16_kernel<<<(int)(TE / 4 / 256), 256, 0, stream>>>(hs, hsb, (int)TE);
    dim3 g4((unsigned)(EE / 4 / 256), 4, 1);
    cvt4_bf16_kernel<<<g4, 256, 0, stream>>>(Wq, Wk, Wv, Wo, wqb, wkb, wvb, wob);

    dim3 gqkv(T_TOT / 128, E_DIM / 128, 3);
    qkv_gemm_kernel<<<gqkv, 256, 0, stream>>>(hsb, wqb, wkb, wvb, bq, bv, qb, kb, vb);

    rope_kernel<<<(T_TOT * NHEAD * 4) / 256, 256, 0, stream>>>(qb, kb, cosb, sinb);

    transpose_v_kernel<<<(T_TOT / 64) * NHEAD, 256, 0, stream>>>(vb, vtb);

    attn_kernel<<<(T_TOT / 64) * NHEAD, 256, 0, stream>>>(qb, kb, vtb, attnb);

    dim3 gout(T_TOT / 128, E_DIM / 128, 1);
    out_gemm_kernel<<<gout, 256, 0, stream>>>(attnb, wob, bo, (float*)d_out);
}